// Round 6
// baseline (729.717 us; speedup 1.0000x reference)
//
#include <hip/hip_runtime.h>
#include <cstdint>

#define DEV __device__ __forceinline__

typedef _Float16 f16;
typedef __attribute__((ext_vector_type(8))) _Float16 f16x8;
typedef __attribute__((ext_vector_type(4))) float f32x4;

DEV unsigned short f2h(float f) {
  f16 h = (f16)f;
  return __builtin_bit_cast(unsigned short, h);
}

DEV void async_ld16(const void* g, void* l) {
  __builtin_amdgcn_global_load_lds(
      (__attribute__((address_space(1))) unsigned int*)(uintptr_t)g,
      (__attribute__((address_space(3))) unsigned int*)(uint32_t)(uintptr_t)l,
      16, 0, 0);
}

// ---------------------------------------------------------------------------
// NT-GEMM: C[M x N] = A[M x K] * B[N x K]^T   (K-contiguous, f16-as-ushort)
// 128x128 tile, BK=64 (2 barriers per 64-K), 4 waves (2x2), 16x16x32 f16 MFMA,
// global_load_lds width=16 staging.
// EPI: 0 = fp16 store (LDS-coalesced), 1 = fp32 store, 2 = fp32 atomicAdd,
//      3 = exp+stats (P' fp16 LDS-coalesced + per-(row,128tile) m/l stats).
// ALPHA: scale A-fragments in-loop by alphaT[ktile][row] fp16 (R5 layout).
// ORDER: within-XCD block order: 0 = mloc-inner, 1 = rest-inner.
// Grid 1D = nt*mt*sl; sl = split-K slices (K param = per-slice depth).
// ---------------------------------------------------------------------------
template <int BM, int BN, int EPI, bool RELU, bool HASBIAS, bool ALPHA, int ORDER>
__global__ __launch_bounds__(256) void gemm_nt(
    const unsigned short* __restrict__ A, const unsigned short* __restrict__ B,
    void* __restrict__ Cp, const float* __restrict__ bias,
    const unsigned short* __restrict__ alp, float* __restrict__ stm,
    float* __restrict__ stl, int Mtot,
    int K, int lda, int ldb, int ldc, int nt, int mt, int sl) {
  constexpr int BK = 64;
  constexpr int WM = BM / 2, WN = BN / 2;
  constexpr int FM = WM / 16, FN = WN / 16;

  __shared__ __align__(16) unsigned short As[BM * BK];   // 16 KB
  __shared__ __align__(16) unsigned short Bs[BN * BK];   // 16 KB
  __shared__ __align__(16) unsigned short Alds[ALPHA ? BM * 32 : 8];

  // ---- XCD-aware swizzle (HW maps linear block id round-robin over 8 XCDs) -
  int mb, nb, zb;
  {
    const int b = blockIdx.x;
    if ((mt & 7) == 0) {
      const int xcd = b & 7;
      const int i = b >> 3;
      const int band_sz = 8 * nt * sl;
      const int band = i / band_sz;
      const int wq = i % band_sz;
      int mloc, rest;
      if (ORDER == 0) { mloc = wq & 7; rest = wq >> 3; }
      else           { rest = wq % (nt * sl); mloc = wq / (nt * sl); }
      mb = xcd + 8 * (band * 8 + mloc);
      nb = rest % nt;
      zb = rest / nt;
    } else {
      nb = b % nt;
      const int t = b / nt;
      mb = t % mt;
      zb = t / mt;
    }
  }

  const int tid = threadIdx.x;
  const int wave = tid >> 6, lane = tid & 63;
  const int wm = (wave >> 1) * WM, wn = (wave & 1) * WN;
  const int bm = mb * BM, bn = nb * BN;
  const size_t koff = (size_t)zb * K;

  const int r8 = tid >> 3;          // row within a 32-row staging group
  const int c8 = (tid & 7) * 8;     // k-offset (8 f16 = 16B)

  if (ALPHA) {
    // stage alphaT slice: (K/128) tiles x BM rows fp16 (8 KB at K=4096,BM=128)
    const int ntile_l = K >> 7;
    const int nu4 = (ntile_l * BM) >> 3;
    const unsigned short* g0 = alp + (size_t)(zb * ntile_l) * Mtot + bm;
    uint4* s = (uint4*)Alds;
    for (int idx = tid; idx < nu4; idx += 256) {
      const int t = idx >> 4;
      const int ru = (idx & 15) << 3;
      s[idx] = *(const uint4*)(g0 + (size_t)t * Mtot + ru);
    }
  }

  f32x4 acc[FM][FN] = {};

  const int kq = (lane >> 4) * 8;
  const int mr = lane & 15;
  const int quad = lane >> 4;

  for (int k0 = 0; k0 < K; k0 += BK) {
#pragma unroll
    for (int p = 0; p < BM / 32; ++p) {
      const unsigned short* g = A + (size_t)(bm + p * 32 + r8) * lda + koff + k0 + c8;
      async_ld16(g, &As[p * 2048 + wave * 512]);
    }
#pragma unroll
    for (int p = 0; p < BN / 32; ++p) {
      const unsigned short* g = B + (size_t)(bn + p * 32 + r8) * ldb + koff + k0 + c8;
      async_ld16(g, &Bs[p * 2048 + wave * 512]);
    }
    __syncthreads();

#pragma unroll
    for (int s = 0; s < 2; ++s) {
      f16x8 av[FM], bv[FN];
#pragma unroll
      for (int i = 0; i < FM; ++i)
        av[i] = *(const f16x8*)(const void*)&As[(wm + i * 16 + mr) * BK + s * 32 + kq];
#pragma unroll
      for (int j = 0; j < FN; ++j)
        bv[j] = *(const f16x8*)(const void*)&Bs[(wn + j * 16 + mr) * BK + s * 32 + kq];

      if (ALPHA) {
        const int tl = (k0 + s * 32) >> 7;
#pragma unroll
        for (int i = 0; i < FM; ++i) {
          const f16 sc = ((const f16*)Alds)[tl * 128 + (wm + i * 16 + mr)];
          av[i] = av[i] * sc;
        }
      }

#pragma unroll
      for (int i = 0; i < FM; ++i)
#pragma unroll
        for (int j = 0; j < FN; ++j)
          acc[i][j] = __builtin_amdgcn_mfma_f32_16x16x32_f16(av[i], bv[j], acc[i][j], 0, 0, 0);
    }

    __syncthreads();
  }

  // --- staged-coalesced fp16 store helpers (EPI 0 / 3) ----------------------
  // i-slice staging tile: 32 rows x 128 cols fp16, row stride 132 (2-way banks)
  unsigned short* Es = (unsigned short*)As;
  const int srow = (wave >> 1) * 16 + quad * 4;          // + r
  const int trow = tid >> 3;                              // 0..31
  const int tcol = (tid & 7) * 16;

  if (EPI == 3) {
    // --- fused exp + per-(row, 128-tile) stats ---------------------------
    float* sred = (float*)As;   // [128][2]
    float* ssum = (float*)Bs;   // [128][2]
    const int wc = wave & 1;
    float mt_[FM][4];
#pragma unroll
    for (int i = 0; i < FM; ++i)
#pragma unroll
      for (int r = 0; r < 4; ++r) {
        float m = acc[i][0][r];
#pragma unroll
        for (int j = 1; j < FN; ++j) m = fmaxf(m, acc[i][j][r]);
        m = fmaxf(m, __shfl_xor(m, 1));
        m = fmaxf(m, __shfl_xor(m, 2));
        m = fmaxf(m, __shfl_xor(m, 4));
        m = fmaxf(m, __shfl_xor(m, 8));
        if (mr == 0) sred[(wm + i * 16 + quad * 4 + r) * 2 + wc] = m;
      }
    __syncthreads();
#pragma unroll
    for (int i = 0; i < FM; ++i)
#pragma unroll
      for (int r = 0; r < 4; ++r) {
        const int row_l = wm + i * 16 + quad * 4 + r;
        mt_[i][r] = fmaxf(sred[row_l * 2], sred[row_l * 2 + 1]);
        float l = 0.f;
#pragma unroll
        for (int j = 0; j < FN; ++j) {
          float e = __expf(acc[i][j][r] - mt_[i][r]);
          acc[i][j][r] = e;       // keep for staged store
          l += e;
        }
        l += __shfl_xor(l, 1);
        l += __shfl_xor(l, 2);
        l += __shfl_xor(l, 4);
        l += __shfl_xor(l, 8);
        if (mr == 0) ssum[row_l * 2 + wc] = l;
      }
    __syncthreads();
    if (wc == 0 && mr == 0) {
#pragma unroll
      for (int i = 0; i < FM; ++i)
#pragma unroll
        for (int r = 0; r < 4; ++r) {
          const int row_l = wm + i * 16 + quad * 4 + r;
          stm[(size_t)nb * Mtot + bm + row_l] = mt_[i][r];
          stl[(size_t)nb * Mtot + bm + row_l] = ssum[row_l * 2] + ssum[row_l * 2 + 1];
        }
    }
    // staged-coalesced P' store (sred/As region reused; ssum/Bs untouched? Bs
    // is read above only before this point -- safe after a barrier)
#pragma unroll
    for (int i = 0; i < FM; ++i) {
      __syncthreads();
#pragma unroll
      for (int j = 0; j < FN; ++j) {
        const int col = wn + j * 16 + mr;
#pragma unroll
        for (int r = 0; r < 4; ++r)
          Es[(srow + r) * 132 + col] = f2h(acc[i][j][r]);
      }
      __syncthreads();
      uint4 d0 = *(const uint4*)&Es[trow * 132 + tcol];
      uint4 d1 = *(const uint4*)&Es[trow * 132 + tcol + 8];
      unsigned short* gp = (unsigned short*)Cp +
          (size_t)(bm + (trow & 15) + (trow >> 4) * WM + i * 16) * ldc + bn + tcol;
      *(uint4*)gp = d0;
      *(uint4*)(gp + 8) = d1;
    }
    return;
  }

  if (EPI == 0) {
    // fp16 output via LDS-coalesced staging
#pragma unroll
    for (int i = 0; i < FM; ++i) {
      __syncthreads();
#pragma unroll
      for (int j = 0; j < FN; ++j) {
        const int col = wn + j * 16 + mr;
        float bv_ = HASBIAS ? bias[bn + col] : 0.f;
#pragma unroll
        for (int r = 0; r < 4; ++r) {
          float v = acc[i][j][r] + bv_;
          if (RELU) v = fmaxf(v, 0.f);
          Es[(srow + r) * 132 + col] = f2h(v);
        }
      }
      __syncthreads();
      uint4 d0 = *(const uint4*)&Es[trow * 132 + tcol];
      uint4 d1 = *(const uint4*)&Es[trow * 132 + tcol + 8];
      unsigned short* gp = (unsigned short*)Cp +
          (size_t)(bm + (trow & 15) + (trow >> 4) * WM + i * 16) * ldc + bn + tcol;
      *(uint4*)gp = d0;
      *(uint4*)(gp + 8) = d1;
    }
    return;
  }

  // --- fp32 epilogues (store / atomic) -------------------------------------
#pragma unroll
  for (int i = 0; i < FM; ++i) {
#pragma unroll
    for (int j = 0; j < FN; ++j) {
      const int col = bn + wn + j * 16 + mr;
      float bv_ = 0.f;
      if (HASBIAS) bv_ = bias[col];
#pragma unroll
      for (int r = 0; r < 4; ++r) {
        const int row = bm + wm + i * 16 + quad * 4 + r;
        float v = acc[i][j][r];
        if (HASBIAS) v += bv_;
        if (RELU) v = fmaxf(v, 0.f);
        if (EPI == 2)
          atomicAdd(&((float*)Cp)[(size_t)row * ldc + col], v);
        else
          ((float*)Cp)[(size_t)row * ldc + col] = v;
      }
    }
  }
}

// per-row combine: M = max_t m_t, L = sum_t l_t*exp(m_t-M)
// writes alpha TRANSPOSED: alp[tile * Mtot + row] = exp(m_t - M) / L
__global__ __launch_bounds__(256) void combine_alpha(
    const float* __restrict__ stm, const float* __restrict__ stl,
    unsigned short* __restrict__ alp, int ntile, int Mtot) {
  const int row = blockIdx.x * 4 + (threadIdx.x >> 6);
  const int t = threadIdx.x & 63;
  float m = (t < ntile) ? stm[(size_t)t * Mtot + row] : -1e30f;
  float M = m;
#pragma unroll
  for (int o = 1; o < 64; o <<= 1) M = fmaxf(M, __shfl_xor(M, o));
  float l = (t < ntile) ? stl[(size_t)t * Mtot + row] : 0.f;
  float c = l * __expf(m - M);
#pragma unroll
  for (int o = 1; o < 64; o <<= 1) c += __shfl_xor(c, o);
  if (t < ntile) alp[(size_t)t * Mtot + row] = f2h(__expf(m - M) / c);
}

__global__ __launch_bounds__(256) void cvt_f16(const float* __restrict__ in,
                                               unsigned short* __restrict__ out, int n) {
  int i = blockIdx.x * 256 + threadIdx.x;
  if (i < n) out[i] = f2h(in[i]);
}

__global__ __launch_bounds__(256) void bias_fill(float* __restrict__ out,
                                                 const float* __restrict__ b, int d) {
  int i = blockIdx.x * 256 + threadIdx.x;
  out[i] = b[i % d];
}

// V [8192 x 768] fp32 -> vT [768 x 8192] fp16
__global__ __launch_bounds__(256) void vt_kernel(const float* __restrict__ V,
                                                 unsigned short* __restrict__ vT) {
  __shared__ float t[32][33];
  const int bx = blockIdx.x, by = blockIdx.y;
  const int x = threadIdx.x, y = threadIdx.y;  // (32, 8)
#pragma unroll
  for (int r = 0; r < 4; ++r)
    t[y + r * 8][x] = V[(size_t)(by * 32 + y + r * 8) * 768 + bx * 32 + x];
  __syncthreads();
#pragma unroll
  for (int r = 0; r < 4; ++r)
    vT[(size_t)(bx * 32 + y + r * 8) * 8192 + by * 32 + x] = f2h(t[x][y + r * 8]);
}

// ---------------------------------------------------------------------------
extern "C" void kernel_launch(void* const* d_in, const int* in_sizes, int n_in,
                              void* d_out, int out_size, void* d_ws, size_t ws_size,
                              hipStream_t stream) {
  const int N = 8192, D = 768, DFF = 2048;
  const float* Q  = (const float*)d_in[0];
  const float* Km = (const float*)d_in[1];
  const float* V  = (const float*)d_in[2];
  const float* W1 = (const float*)d_in[3];
  const float* b1 = (const float*)d_in[4];
  const float* W2 = (const float*)d_in[5];
  const float* b2 = (const float*)d_in[6];

  char* w = (char*)d_ws;
  size_t off = 0;
  auto take = [&](size_t bytes) { void* p = w + off; off += bytes; return p; };
  unsigned short* qh   = (unsigned short*)take((size_t)N * D * 2);
  unsigned short* kh   = (unsigned short*)take((size_t)N * D * 2);
  unsigned short* vT   = (unsigned short*)take((size_t)N * D * 2);
  unsigned short* ctx16= (unsigned short*)take((size_t)N * D * 2);
  float*          ctx32= (float*)take((size_t)N * D * 4);
  unsigned short* hb   = (unsigned short*)take((size_t)N * DFF * 2);
  unsigned short* w1h  = (unsigned short*)take((size_t)DFF * D * 2);
  unsigned short* w2h  = (unsigned short*)take((size_t)D * DFF * 2);
  float*          stm  = (float*)take((size_t)64 * N * 4);
  float*          stl  = (float*)take((size_t)64 * N * 4);
  unsigned short* alp  = (unsigned short*)take((size_t)64 * N * 2);  // [tile][row]
  unsigned short* Pp   = (unsigned short*)take((size_t)N * N * 2);   // P' fp16, 128 MB
  (void)ws_size;

  cvt_f16<<<(N * D) / 256, 256, 0, stream>>>(Q, qh, N * D);
  cvt_f16<<<(N * D) / 256, 256, 0, stream>>>(Km, kh, N * D);
  vt_kernel<<<dim3(D / 32, N / 32), dim3(32, 8), 0, stream>>>(V, vT);
  cvt_f16<<<(DFF * D) / 256, 256, 0, stream>>>(W1, w1h, DFF * D);
  cvt_f16<<<(D * DFF) / 256, 256, 0, stream>>>(W2, w2h, D * DFF);
  hipMemsetAsync(ctx32, 0, (size_t)N * D * 4, stream);
  bias_fill<<<(N * D) / 256, 256, 0, stream>>>((float*)d_out, b2, D);

  {  // QK^T with fused exp + stats: P' fp16 [8192x8192], m/l per (row,tile)
    const int nt = N / 128, mt = N / 128;
    gemm_nt<128, 128, 3, false, false, false, 0>
        <<<nt * mt, 256, 0, stream>>>(
            qh, kh, Pp, nullptr, nullptr, stm, stl, N,
            D, D, D, N, nt, mt, 1);
  }
  combine_alpha<<<N / 4, 256, 0, stream>>>(stm, stl, alp, 64, N);
  {  // ctx32 += (alphaT .* P') . V  — split-K sl=2, fp32 atomics
    const int nt = D / 128, mt = N / 128, sl = 2;
    gemm_nt<128, 128, 2, false, false, true, 1>
        <<<nt * mt * sl, 256, 0, stream>>>(
            Pp, vT, ctx32, nullptr, alp, nullptr, nullptr, N,
            N / sl, N, N, D, nt, mt, sl);
  }
  cvt_f16<<<(N * D) / 256, 256, 0, stream>>>(ctx32, ctx16, N * D);

  {  // h = relu(ctx . W1^T + b1)  fp16 (LDS-coalesced store)
    const int nt = DFF / 128, mt = N / 128;
    gemm_nt<128, 128, 0, true, true, false, 1>
        <<<nt * mt, 256, 0, stream>>>(
            ctx16, w1h, hb, b1, nullptr, nullptr, nullptr, N,
            D, D, D, DFF, nt, mt, 1);
  }
  {  // out += h . W2^T  (bias pre-filled) — split-K sl=2, fp32 atomics
    const int nt = D / 128, mt = N / 128, sl = 2;
    gemm_nt<128, 128, 2, false, false, false, 1>
        <<<nt * mt * sl, 256, 0, stream>>>(
            hb, w2h, (float*)d_out, nullptr, nullptr, nullptr, nullptr, N,
            DFF / sl, DFF, DFF, D, nt, mt, sl);
  }
}

// Round 7
// 709.210 us; speedup vs baseline: 1.0289x; 1.0289x over previous
//
#include <hip/hip_runtime.h>
#include <cstdint>

#define DEV __device__ __forceinline__

typedef _Float16 f16;
typedef __attribute__((ext_vector_type(8))) _Float16 f16x8;
typedef __attribute__((ext_vector_type(4))) float f32x4;

DEV unsigned short f2h(float f) {
  f16 h = (f16)f;
  return __builtin_bit_cast(unsigned short, h);
}

DEV void async_ld16(const void* g, void* l) {
  __builtin_amdgcn_global_load_lds(
      (__attribute__((address_space(1))) unsigned int*)(uintptr_t)g,
      (__attribute__((address_space(3))) unsigned int*)(uint32_t)(uintptr_t)l,
      16, 0, 0);
}

// ---------------------------------------------------------------------------
// NT-GEMM: C[M x N] = A[M x K] * B[N x K]^T   (K-contiguous, f16-as-ushort)
// 128x128 tile, BK=32 (R7: reverted from BK=64 — 128B LDS row stride put all
// 16 fragment rows on one bank phase, conflicts 1.3e7->3.8e7, QK +46us),
// 4 waves (2x2), 16x16x32 f16 MFMA, global_load_lds width=16 staging.
// EPI: 0 = fp16 store (LDS-coalesced), 1 = fp32 store, 2 = fp32 atomicAdd,
//      3 = exp+stats (P' fp16 LDS-coalesced + per-(row,128tile) m/l stats).
// ALPHA: scale A-fragments in-loop by alphaT[ktile][row] fp16 (R5 layout).
// ORDER: within-XCD block order: 0 = mloc-inner, 1 = rest-inner.
// Grid 1D = nt*mt*sl; sl = split-K slices (K param = per-slice depth).
// ---------------------------------------------------------------------------
template <int BM, int BN, int EPI, bool RELU, bool HASBIAS, bool ALPHA, int ORDER>
__global__ __launch_bounds__(256) void gemm_nt(
    const unsigned short* __restrict__ A, const unsigned short* __restrict__ B,
    void* __restrict__ Cp, const float* __restrict__ bias,
    const unsigned short* __restrict__ alp, float* __restrict__ stm,
    float* __restrict__ stl, int Mtot,
    int K, int lda, int ldb, int ldc, int nt, int mt, int sl) {
  constexpr int BK = 32;
  constexpr int WM = BM / 2, WN = BN / 2;
  constexpr int FM = WM / 16, FN = WN / 16;

  // combined As|Bs so the epilogue staging tile (32x132 halves = 8.4 KB) can
  // overlay both without out-of-bounds UB
  __shared__ __align__(16) unsigned short Sm[BM * BK + BN * BK];  // 16 KB
  unsigned short* As = Sm;
  unsigned short* Bs = Sm + BM * BK;
  __shared__ __align__(16) unsigned short Alds[ALPHA ? BM * 32 : 8];

  // ---- XCD-aware swizzle (HW maps linear block id round-robin over 8 XCDs) -
  int mb, nb, zb;
  {
    const int b = blockIdx.x;
    if ((mt & 7) == 0) {
      const int xcd = b & 7;
      const int i = b >> 3;
      const int band_sz = 8 * nt * sl;
      const int band = i / band_sz;
      const int wq = i % band_sz;
      int mloc, rest;
      if (ORDER == 0) { mloc = wq & 7; rest = wq >> 3; }
      else           { rest = wq % (nt * sl); mloc = wq / (nt * sl); }
      mb = xcd + 8 * (band * 8 + mloc);
      nb = rest % nt;
      zb = rest / nt;
    } else {
      nb = b % nt;
      const int t = b / nt;
      mb = t % mt;
      zb = t / mt;
    }
  }

  const int tid = threadIdx.x;
  const int wave = tid >> 6, lane = tid & 63;
  const int wm = (wave >> 1) * WM, wn = (wave & 1) * WN;
  const int bm = mb * BM, bn = nb * BN;
  const size_t koff = (size_t)zb * K;

  const int r4 = tid >> 2;
  const int c4 = (tid & 3) * 8;

  if (ALPHA) {
    // stage alphaT slice: (K/128) tiles x BM rows fp16 (8 KB at K=4096,BM=128)
    const int ntile_l = K >> 7;
    const int nu4 = (ntile_l * BM) >> 3;
    const unsigned short* g0 = alp + (size_t)(zb * ntile_l) * Mtot + bm;
    uint4* s = (uint4*)Alds;
    for (int idx = tid; idx < nu4; idx += 256) {
      const int t = idx >> 4;
      const int ru = (idx & 15) << 3;
      s[idx] = *(const uint4*)(g0 + (size_t)t * Mtot + ru);
    }
  }

  f32x4 acc[FM][FN] = {};

  const int kq = (lane >> 4) * 8;
  const int mr = lane & 15;
  const int quad = lane >> 4;

  for (int k0 = 0; k0 < K; k0 += BK) {
#pragma unroll
    for (int p = 0; p < BM / 64; ++p) {
      const unsigned short* g = A + (size_t)(bm + p * 64 + r4) * lda + koff + k0 + c4;
      async_ld16(g, &As[p * 2048 + wave * 512]);
    }
#pragma unroll
    for (int p = 0; p < BN / 64; ++p) {
      const unsigned short* g = B + (size_t)(bn + p * 64 + r4) * ldb + koff + k0 + c4;
      async_ld16(g, &Bs[p * 2048 + wave * 512]);
    }
    __syncthreads();

    f16x8 av[FM], bv[FN];
#pragma unroll
    for (int i = 0; i < FM; ++i)
      av[i] = *(const f16x8*)(const void*)&As[(wm + i * 16 + mr) * BK + kq];
#pragma unroll
    for (int j = 0; j < FN; ++j)
      bv[j] = *(const f16x8*)(const void*)&Bs[(wn + j * 16 + mr) * BK + kq];

    if (ALPHA) {
      const int tl = k0 >> 7;  // slice-local tile
#pragma unroll
      for (int i = 0; i < FM; ++i) {
        const f16 sc = ((const f16*)Alds)[tl * 128 + (wm + i * 16 + mr)];
        av[i] = av[i] * sc;
      }
    }

#pragma unroll
    for (int i = 0; i < FM; ++i)
#pragma unroll
      for (int j = 0; j < FN; ++j)
        acc[i][j] = __builtin_amdgcn_mfma_f32_16x16x32_f16(av[i], bv[j], acc[i][j], 0, 0, 0);

    __syncthreads();
  }

  // --- staged-coalesced fp16 store helpers (EPI 0 / 3) ----------------------
  // i-slice staging tile: 32 rows x 128 cols fp16, row stride 132 (conflict-
  // free: 4 quads land on bank phases 0/8/16/24, 16 cols span 8 banks, 2/bank)
  unsigned short* Es = Sm;
  const int srow = (wave >> 1) * 16 + quad * 4;          // + r
  const int trow = tid >> 3;                              // 0..31
  const int tcol = (tid & 7) * 16;

  if (EPI == 3) {
    // --- fused exp + per-(row, 128-tile) stats ---------------------------
    float* sred = (float*)As;   // [128][2]
    float* ssum = (float*)Bs;   // [128][2]
    const int wc = wave & 1;
    float mt_[FM][4];
#pragma unroll
    for (int i = 0; i < FM; ++i)
#pragma unroll
      for (int r = 0; r < 4; ++r) {
        float m = acc[i][0][r];
#pragma unroll
        for (int j = 1; j < FN; ++j) m = fmaxf(m, acc[i][j][r]);
        m = fmaxf(m, __shfl_xor(m, 1));
        m = fmaxf(m, __shfl_xor(m, 2));
        m = fmaxf(m, __shfl_xor(m, 4));
        m = fmaxf(m, __shfl_xor(m, 8));
        if (mr == 0) sred[(wm + i * 16 + quad * 4 + r) * 2 + wc] = m;
      }
    __syncthreads();
#pragma unroll
    for (int i = 0; i < FM; ++i)
#pragma unroll
      for (int r = 0; r < 4; ++r) {
        const int row_l = wm + i * 16 + quad * 4 + r;
        mt_[i][r] = fmaxf(sred[row_l * 2], sred[row_l * 2 + 1]);
        float l = 0.f;
#pragma unroll
        for (int j = 0; j < FN; ++j) {
          float e = __expf(acc[i][j][r] - mt_[i][r]);
          acc[i][j][r] = e;       // keep for staged store
          l += e;
        }
        l += __shfl_xor(l, 1);
        l += __shfl_xor(l, 2);
        l += __shfl_xor(l, 4);
        l += __shfl_xor(l, 8);
        if (mr == 0) ssum[row_l * 2 + wc] = l;
      }
    __syncthreads();
    if (wc == 0 && mr == 0) {
#pragma unroll
      for (int i = 0; i < FM; ++i)
#pragma unroll
        for (int r = 0; r < 4; ++r) {
          const int row_l = wm + i * 16 + quad * 4 + r;
          stm[(size_t)nb * Mtot + bm + row_l] = mt_[i][r];
          stl[(size_t)nb * Mtot + bm + row_l] = ssum[row_l * 2] + ssum[row_l * 2 + 1];
        }
    }
    // staged-coalesced P' store (Es overlays As|Bs; ssum reads completed
    // before the barrier at each i-iteration start)
#pragma unroll
    for (int i = 0; i < FM; ++i) {
      __syncthreads();
#pragma unroll
      for (int j = 0; j < FN; ++j) {
        const int col = wn + j * 16 + mr;
#pragma unroll
        for (int r = 0; r < 4; ++r)
          Es[(srow + r) * 132 + col] = f2h(acc[i][j][r]);
      }
      __syncthreads();
      uint4 d0 = *(const uint4*)&Es[trow * 132 + tcol];
      uint4 d1 = *(const uint4*)&Es[trow * 132 + tcol + 8];
      unsigned short* gp = (unsigned short*)Cp +
          (size_t)(bm + (trow & 15) + (trow >> 4) * WM + i * 16) * ldc + bn + tcol;
      *(uint4*)gp = d0;
      *(uint4*)(gp + 8) = d1;
    }
    return;
  }

  if (EPI == 0) {
    // fp16 output via LDS-coalesced staging
#pragma unroll
    for (int i = 0; i < FM; ++i) {
      __syncthreads();
#pragma unroll
      for (int j = 0; j < FN; ++j) {
        const int col = wn + j * 16 + mr;
        float bv_ = HASBIAS ? bias[bn + col] : 0.f;
#pragma unroll
        for (int r = 0; r < 4; ++r) {
          float v = acc[i][j][r] + bv_;
          if (RELU) v = fmaxf(v, 0.f);
          Es[(srow + r) * 132 + col] = f2h(v);
        }
      }
      __syncthreads();
      uint4 d0 = *(const uint4*)&Es[trow * 132 + tcol];
      uint4 d1 = *(const uint4*)&Es[trow * 132 + tcol + 8];
      unsigned short* gp = (unsigned short*)Cp +
          (size_t)(bm + (trow & 15) + (trow >> 4) * WM + i * 16) * ldc + bn + tcol;
      *(uint4*)gp = d0;
      *(uint4*)(gp + 8) = d1;
    }
    return;
  }

  // --- fp32 epilogues (store / atomic) -------------------------------------
#pragma unroll
  for (int i = 0; i < FM; ++i) {
#pragma unroll
    for (int j = 0; j < FN; ++j) {
      const int col = bn + wn + j * 16 + mr;
      float bv_ = 0.f;
      if (HASBIAS) bv_ = bias[col];
#pragma unroll
      for (int r = 0; r < 4; ++r) {
        const int row = bm + wm + i * 16 + quad * 4 + r;
        float v = acc[i][j][r];
        if (HASBIAS) v += bv_;
        if (RELU) v = fmaxf(v, 0.f);
        if (EPI == 2)
          atomicAdd(&((float*)Cp)[(size_t)row * ldc + col], v);
        else
          ((float*)Cp)[(size_t)row * ldc + col] = v;
      }
    }
  }
}

// per-row combine: M = max_t m_t, L = sum_t l_t*exp(m_t-M)
// writes alpha TRANSPOSED: alp[tile * Mtot + row] = exp(m_t - M) / L
__global__ __launch_bounds__(256) void combine_alpha(
    const float* __restrict__ stm, const float* __restrict__ stl,
    unsigned short* __restrict__ alp, int ntile, int Mtot) {
  const int row = blockIdx.x * 4 + (threadIdx.x >> 6);
  const int t = threadIdx.x & 63;
  float m = (t < ntile) ? stm[(size_t)t * Mtot + row] : -1e30f;
  float M = m;
#pragma unroll
  for (int o = 1; o < 64; o <<= 1) M = fmaxf(M, __shfl_xor(M, o));
  float l = (t < ntile) ? stl[(size_t)t * Mtot + row] : 0.f;
  float c = l * __expf(m - M);
#pragma unroll
  for (int o = 1; o < 64; o <<= 1) c += __shfl_xor(c, o);
  if (t < ntile) alp[(size_t)t * Mtot + row] = f2h(__expf(m - M) / c);
}

__global__ __launch_bounds__(256) void cvt_f16(const float* __restrict__ in,
                                               unsigned short* __restrict__ out, int n) {
  int i = blockIdx.x * 256 + threadIdx.x;
  if (i < n) out[i] = f2h(in[i]);
}

__global__ __launch_bounds__(256) void bias_fill(float* __restrict__ out,
                                                 const float* __restrict__ b, int d) {
  int i = blockIdx.x * 256 + threadIdx.x;
  out[i] = b[i % d];
}

// V [8192 x 768] fp32 -> vT [768 x 8192] fp16
__global__ __launch_bounds__(256) void vt_kernel(const float* __restrict__ V,
                                                 unsigned short* __restrict__ vT) {
  __shared__ float t[32][33];
  const int bx = blockIdx.x, by = blockIdx.y;
  const int x = threadIdx.x, y = threadIdx.y;  // (32, 8)
#pragma unroll
  for (int r = 0; r < 4; ++r)
    t[y + r * 8][x] = V[(size_t)(by * 32 + y + r * 8) * 768 + bx * 32 + x];
  __syncthreads();
#pragma unroll
  for (int r = 0; r < 4; ++r)
    vT[(size_t)(bx * 32 + y + r * 8) * 8192 + by * 32 + x] = f2h(t[x][y + r * 8]);
}

// ---------------------------------------------------------------------------
extern "C" void kernel_launch(void* const* d_in, const int* in_sizes, int n_in,
                              void* d_out, int out_size, void* d_ws, size_t ws_size,
                              hipStream_t stream) {
  const int N = 8192, D = 768, DFF = 2048;
  const float* Q  = (const float*)d_in[0];
  const float* Km = (const float*)d_in[1];
  const float* V  = (const float*)d_in[2];
  const float* W1 = (const float*)d_in[3];
  const float* b1 = (const float*)d_in[4];
  const float* W2 = (const float*)d_in[5];
  const float* b2 = (const float*)d_in[6];

  char* w = (char*)d_ws;
  size_t off = 0;
  auto take = [&](size_t bytes) { void* p = w + off; off += bytes; return p; };
  unsigned short* qh   = (unsigned short*)take((size_t)N * D * 2);
  unsigned short* kh   = (unsigned short*)take((size_t)N * D * 2);
  unsigned short* vT   = (unsigned short*)take((size_t)N * D * 2);
  unsigned short* ctx16= (unsigned short*)take((size_t)N * D * 2);
  float*          ctx32= (float*)take((size_t)N * D * 4);
  unsigned short* hb   = (unsigned short*)take((size_t)N * DFF * 2);
  unsigned short* w1h  = (unsigned short*)take((size_t)DFF * D * 2);
  unsigned short* w2h  = (unsigned short*)take((size_t)D * DFF * 2);
  float*          stm  = (float*)take((size_t)64 * N * 4);
  float*          stl  = (float*)take((size_t)64 * N * 4);
  unsigned short* alp  = (unsigned short*)take((size_t)64 * N * 2);  // [tile][row]
  unsigned short* Pp   = (unsigned short*)take((size_t)N * N * 2);   // P' fp16, 128 MB
  (void)ws_size;

  cvt_f16<<<(N * D) / 256, 256, 0, stream>>>(Q, qh, N * D);
  cvt_f16<<<(N * D) / 256, 256, 0, stream>>>(Km, kh, N * D);
  vt_kernel<<<dim3(D / 32, N / 32), dim3(32, 8), 0, stream>>>(V, vT);
  cvt_f16<<<(DFF * D) / 256, 256, 0, stream>>>(W1, w1h, DFF * D);
  cvt_f16<<<(D * DFF) / 256, 256, 0, stream>>>(W2, w2h, D * DFF);
  hipMemsetAsync(ctx32, 0, (size_t)N * D * 4, stream);
  bias_fill<<<(N * D) / 256, 256, 0, stream>>>((float*)d_out, b2, D);

  {  // QK^T with fused exp + stats: P' fp16 [8192x8192], m/l per (row,tile)
    const int nt = N / 128, mt = N / 128;
    gemm_nt<128, 128, 3, false, false, false, 0>
        <<<nt * mt, 256, 0, stream>>>(
            qh, kh, Pp, nullptr, nullptr, stm, stl, N,
            D, D, D, N, nt, mt, 1);
  }
  combine_alpha<<<N / 4, 256, 0, stream>>>(stm, stl, alp, 64, N);
  {  // ctx32 += (alphaT .* P') . V  — split-K sl=2, fp32 atomics
    const int nt = D / 128, mt = N / 128, sl = 2;
    gemm_nt<128, 128, 2, false, false, true, 1>
        <<<nt * mt * sl, 256, 0, stream>>>(
            Pp, vT, ctx32, nullptr, alp, nullptr, nullptr, N,
            N / sl, N, N, D, nt, mt, sl);
  }
  cvt_f16<<<(N * D) / 256, 256, 0, stream>>>(ctx32, ctx16, N * D);

  {  // h = relu(ctx . W1^T + b1)  fp16 (LDS-coalesced store)
    const int nt = DFF / 128, mt = N / 128;
    gemm_nt<128, 128, 0, true, true, false, 1>
        <<<nt * mt, 256, 0, stream>>>(
            ctx16, w1h, hb, b1, nullptr, nullptr, nullptr, N,
            D, D, D, DFF, nt, mt, 1);
  }
  {  // out += h . W2^T  (bias pre-filled) — split-K sl=2, fp32 atomics
    const int nt = D / 128, mt = N / 128, sl = 2;
    gemm_nt<128, 128, 2, false, false, false, 1>
        <<<nt * mt * sl, 256, 0, stream>>>(
            hb, w2h, (float*)d_out, nullptr, nullptr, nullptr, nullptr, N,
            DFF / sl, DFF, DFF, D, nt, mt, sl);
  }
}